// Round 7
// baseline (105.245 us; speedup 1.0000x reference)
//
#include <hip/hip_runtime.h>
#include <hip/hip_fp16.h>
#include <stdint.h>

#define NH 32   // heads (fixed by table shapes)

__device__ __forceinline__ float bf_to_f(uint16_t u)
{
    return __uint_as_float(((uint32_t)u) << 16);
}

// Async global->LDS 16B copy. LDS dest must be linear in lane order (rule #21):
// T is pre-swizzled in prep, both copy sides stay linear, swizzle applied on
// the LDS read address.
__device__ __forceinline__ void cp16(const void* g, void* l)
{
    __builtin_amdgcn_global_load_lds(
        (const __attribute__((address_space(1))) void*)g,
        (__attribute__((address_space(3))) void*)l, 16, 0, 0);
}

// Block-wide dtype sniff on first 4096 B of spd_table. bf16 N(0,1) never has
// exp field >= 0x89; fp32 low halves do with prob ~1. Returns 1 if fp32.
__device__ __forceinline__ int block_detect_fp32(const uint16_t* p16, int tid,
                                                 int* s_flag)
{
    if (tid == 0) *s_flag = 0;
    __syncthreads();
    const ushort4* p = (const ushort4*)p16;
    ushort4 a = p[tid * 2];
    ushort4 b = p[tid * 2 + 1];
    int big = 0;
    big |= (((a.x >> 7) & 0xFF) >= 0x89); big |= (((a.y >> 7) & 0xFF) >= 0x89);
    big |= (((a.z >> 7) & 0xFF) >= 0x89); big |= (((a.w >> 7) & 0xFF) >= 0x89);
    big |= (((b.x >> 7) & 0xFF) >= 0x89); big |= (((b.y >> 7) & 0xFF) >= 0x89);
    big |= (((b.z >> 7) & 0xFF) >= 0x89); big |= (((b.w >> 7) & 0xFF) >= 0x89);
    if (big) atomicOr(s_flag, 1);
    __syncthreads();
    return *s_flag;
}

// ---------------------------------------------------------------------------
// Fused prep (R12 layout: fp16 T).
//  threads [0, totalT): T16[d][e][k] = fp16( sum_h etab[e][h]*W[d,h,k] ).
//    Row = 32 halves = 64 B = 4 16-B groups. Content group g = k>>3 stored at
//    slot g ^ ((e>>1)&3); a read of content m at slot m^((e>>1)&3) lands on
//    bank-quad (e&1)<<2 | (m ^ ((e>>1)&3)) — bijective in e&7 at fixed m.
//    fp16 numerically safe: |T| <~ 30, rel err 2^-11 (passed, absmax 0.5).
//  threads [totalT, totalT+spd_n): spdT[h][s] = spd[s][h] fp32 (transposed).
// ---------------------------------------------------------------------------
__global__ __launch_bounds__(256) void prep(
    const void* __restrict__ edge_table,
    const void* __restrict__ W,
    const void* __restrict__ spd,
    uint16_t* __restrict__ T16,
    float* __restrict__ spdT,
    int totalT, int spd_n)
{
    __shared__ int s_flag;
    const int tid = threadIdx.x;
    const int is_fp32 = block_detect_fp32((const uint16_t*)spd, tid, &s_flag);
    int g = blockIdx.x * 256 + tid;
    if (g < totalT) {
        int d = g >> 10, e = (g >> 5) & 31, k = g & 31;
        float acc = 0.f;
        if (is_fp32) {
            const float* et = (const float*)edge_table + e * NH;
            const float* w  = (const float*)W + d * NH * NH + k;
#pragma unroll
            for (int h = 0; h < NH; ++h) acc += et[h] * w[h * NH];
        } else {
            const uint16_t* et = (const uint16_t*)edge_table + e * NH;
            const uint16_t* w  = (const uint16_t*)W + d * NH * NH + k;
#pragma unroll
            for (int h = 0; h < NH; ++h) acc += bf_to_f(et[h]) * bf_to_f(w[h * NH]);
        }
        int slot = (k >> 3) ^ ((e >> 1) & 3);              // XOR bank swizzle
        int idx  = (((d << 5) | e) << 5) + (slot << 3) + (k & 7);
        __half hv = __float2half(acc);
        T16[idx] = *(const uint16_t*)&hv;
    } else {
        int i = g - totalT;
        if (i < spd_n) {
            float v = is_fp32 ? ((const float*)spd)[i]
                              : bf_to_f(((const uint16_t*)spd)[i]);
            int s = i >> 5, h = i & 31;                    // input [s][h]
            spdT[h * (spd_n >> 5) + s] = v;                // output [h][s]
        }
    }
}

// ---------------------------------------------------------------------------
// Main kernel (R13 = R12 + k-half tile split).
// R12's residual (~26.5 us vs ~13 us overlapped model) is write-stream
// BURSTINESS: 256-pair tiles alternate ~8 us gather windows (HBM-write idle)
// with ~5 us store bursts (gather idle), plus a 5.3 us final-tile tail.
// Fix with zero added traffic: 128-pair tiles, k-half split by WAVE PAIR
// (kh = t>>7): waves 0-1 own heads 0..15, waves 2-3 own heads 16..31.
//  - stores stay perfectly coalesced (256 B contiguous per wave instr)
//  - edge rows read twice per block but dedup in L1/L2 (no HBM delta)
//  - per-thread stores 64 -> 32: below the vmcnt=63 hardware counter cap,
//    so the compiler's next-tile load guard stops force-draining stores
//  - store bursts every ~2-3 us keep the write pipe continuously fed;
//    final tail halves to ~2.7 us
//  - live accs 32 -> 16: lower VGPR
// Order preserved from R10/R12: next-tile LOADS first, stores LAST (R11
// showed store-before-load order stalls on vmcnt false coupling).
// LDS 40 KiB, 2 blocks/CU, grid 512 persistent, 4 tiles/block.
// ---------------------------------------------------------------------------
__global__ __launch_bounds__(256, 2) void bond2d(
    const int* __restrict__ spatial,
    const int* __restrict__ edge,
    const float4* __restrict__ SgT,      // spdT as float4, NH*ns floats
    const float4* __restrict__ Tg,       // pre-swizzled fp16 T as float4
    float* __restrict__ out,
    int npairs, int D, int ns, int ntiles, int gridsz)
{
    __shared__ float4 Tl[2048];          // 32 KiB: D(<=16) x 32 e x 32 k fp16
    __shared__ float4 Sl4[512];          // 8 KiB : 32 h x 64 s fp32
    const float* Sl = (const float*)Sl4;

    const int t  = threadIdx.x;
    const int kh = t >> 7;               // k-half owned by this wave pair
    const int lp = t & 127;              // local pair within tile
    const bool small_ns = (ns <= 64);
    const float* SgTf = (const float*)SgT;

    // ---- stage T (D*128 float4) + spd once; the only barrier ----
    for (int i = t; i < D * 128; i += 256)
        cp16(Tg + i, Tl + i);
    if (small_ns) {
        const int nsf4 = (NH * ns) >> 2;
        for (int i = t; i < nsf4; i += 256)
            cp16(SgT + i, Sl4 + i);
    }

    // ---- prefetch tile 0 while the stage drains ----
    int tile = blockIdx.x;
    int  pc  = tile * 128 + lp;
    bool vc  = (pc < npairs);
    int  pcc = vc ? pc : 0;
    int  sc  = spatial[pcc];
    int4 c0, c1, c2, c3;
    if (D == 16) {
        const int4* er = (const int4*)(edge + (size_t)pcc * 16);
        c0 = er[0]; c1 = er[1]; c2 = er[2]; c3 = er[3];
    }

    __syncthreads();                     // cp16s drained (vmcnt0 at barrier)

    if (D == 16) {
        for (;;) {
            // issue next tile's loads now — they land under the gather
            const int  tn  = tile + gridsz;
            const bool hn  = (tn < ntiles);
            int  pn = tn * 128 + lp;
            bool vn = hn && (pn < npairs);
            int  pnn = vn ? pn : 0;
            int  sn = 0;
            int4 n0, n1, n2, n3;
            if (hn) {
                sn = spatial[pnn];
                const int4* er = (const int4*)(edge + (size_t)pnn * 16);
                n0 = er[0]; n1 = er[1]; n2 = er[2]; n3 = er[3];
            }

            int ev[16];
            ev[0]=c0.x;  ev[1]=c0.y;  ev[2]=c0.z;  ev[3]=c0.w;
            ev[4]=c1.x;  ev[5]=c1.y;  ev[6]=c1.z;  ev[7]=c1.w;
            ev[8]=c2.x;  ev[9]=c2.y;  ev[10]=c2.z; ev[11]=c2.w;
            ev[12]=c3.x; ev[13]=c3.y; ev[14]=c3.z; ev[15]=c3.w;

            float acc[16];
#pragma unroll
            for (int k = 0; k < 16; ++k) acc[k] = 0.f;

            const char* Tb = (const char*)Tl;
            const int mbase = kh << 5;               // byte offset of kh's groups
#pragma unroll
            for (int d = 0; d < 16; ++d) {
                int e    = ev[d];
                int base = (((d << 5) | e) << 6);    // bytes (64 B/row)
                int sw   = ((e >> 1) & 3) << 4;
#pragma unroll
                for (int mm = 0; mm < 2; ++mm) {
                    uint4 w = *(const uint4*)(Tb + base + ((mbase + (mm << 4)) ^ sw));
                    float2 f0 = __half22float2(*(const __half2*)&w.x);
                    float2 f1 = __half22float2(*(const __half2*)&w.y);
                    float2 f2 = __half22float2(*(const __half2*)&w.z);
                    float2 f3 = __half22float2(*(const __half2*)&w.w);
                    acc[8*mm+0] += f0.x; acc[8*mm+1] += f0.y;
                    acc[8*mm+2] += f1.x; acc[8*mm+3] += f1.y;
                    acc[8*mm+4] += f2.x; acc[8*mm+5] += f2.y;
                    acc[8*mm+6] += f3.x; acc[8*mm+7] += f3.y;
                }
            }

            if (vc) {
                const float rs = 1.0f / (sc ? (float)sc : 1.0f);
                const int hb = kh * 16;
                float* o0 = out + pc;                        // phi_spd
                float* o1 = out + (size_t)NH * npairs + pc;  // phi_edge
#pragma unroll
                for (int j = 0; j < 16; ++j) {
                    o1[(size_t)(hb + j) * npairs] = acc[j] * rs;
                    o0[(size_t)(hb + j) * npairs] =
                        small_ns ? Sl[(hb + j) * ns + sc]
                                 : SgTf[(size_t)(hb + j) * ns + sc];
                }
            }

            if (!hn) break;
            tile = tn; pc = pn; vc = vn; pcc = pnn; sc = sn;
            c0 = n0; c1 = n1; c2 = n2; c3 = n3;
        }
    } else {
        // generic-D fallback (not hit on this bench)
        for (; tile < ntiles; tile += gridsz) {
            int  p  = tile * 128 + lp;
            bool v  = (p < npairs);
            int  pp = v ? p : 0;
            int  s  = spatial[pp];
            const int* erow = edge + (size_t)pp * D;

            float acc[16];
#pragma unroll
            for (int k = 0; k < 16; ++k) acc[k] = 0.f;

            const char* Tb = (const char*)Tl;
            const int mbase = kh << 5;
            for (int d = 0; d < D; ++d) {
                int e    = erow[d];
                int base = (((d << 5) | e) << 6);
                int sw   = ((e >> 1) & 3) << 4;
#pragma unroll
                for (int mm = 0; mm < 2; ++mm) {
                    uint4 w = *(const uint4*)(Tb + base + ((mbase + (mm << 4)) ^ sw));
                    float2 f0 = __half22float2(*(const __half2*)&w.x);
                    float2 f1 = __half22float2(*(const __half2*)&w.y);
                    float2 f2 = __half22float2(*(const __half2*)&w.z);
                    float2 f3 = __half22float2(*(const __half2*)&w.w);
                    acc[8*mm+0] += f0.x; acc[8*mm+1] += f0.y;
                    acc[8*mm+2] += f1.x; acc[8*mm+3] += f1.y;
                    acc[8*mm+4] += f2.x; acc[8*mm+5] += f2.y;
                    acc[8*mm+6] += f3.x; acc[8*mm+7] += f3.y;
                }
            }

            if (v) {
                const float rs = 1.0f / (s ? (float)s : 1.0f);
                const int hb = kh * 16;
                float* o0 = out + p;
                float* o1 = out + (size_t)NH * npairs + p;
#pragma unroll
                for (int j = 0; j < 16; ++j) {
                    o1[(size_t)(hb + j) * npairs] = acc[j] * rs;
                    o0[(size_t)(hb + j) * npairs] =
                        small_ns ? Sl[(hb + j) * ns + s]
                                 : SgTf[(size_t)(hb + j) * ns + s];
                }
            }
        }
    }
}

extern "C" void kernel_launch(void* const* d_in, const int* in_sizes, int n_in,
                              void* d_out, int out_size, void* d_ws, size_t ws_size,
                              hipStream_t stream) {
    // dict order: [0]=spatial_pos [1]=edge_input [2]=max_dist [3]=spd_table
    //             [4]=edge_table  [5]=edge_dis_weight
    const int* spatial = (const int*)d_in[0];
    const int* edge    = (const int*)d_in[1];
    const void* spd    = d_in[3];
    const void* etab   = d_in[4];
    const void* W      = d_in[5];

    long long npairs = in_sizes[0];
    long long etot   = in_sizes[1];
    int D = (int)(etot / (npairs > 0 ? npairs : 1));
    if (D < 1) D = 1;
    if (D > 16) D = 16;
    int spd_n  = in_sizes[3];
    int ns     = spd_n >> 5;          // spatial vocab (64 here)
    int totalT = D * 1024;

    uint16_t* T16 = (uint16_t*)d_ws;            // D*1024 fp16, pre-swizzled
    float*    spdT = (float*)(T16 + totalT);    // spd_n fp32, transposed [h][s]

    prep<<<(totalT + spd_n + 255) / 256, 256, 0, stream>>>(
        etab, W, spd, T16, spdT, totalT, spd_n);

    int ntiles = (int)((npairs + 127) / 128);
    int gridsz = ntiles < 512 ? ntiles : 512;
    bond2d<<<gridsz, 256, 0, stream>>>(spatial, edge, (const float4*)spdT,
                                       (const float4*)T16, (float*)d_out,
                                       (int)npairs, D, ns, ntiles, gridsz);
}